// Round 11
// baseline (152.825 us; speedup 1.0000x reference)
//
#include <hip/hip_runtime.h>
#include <stdint.h>
#include <stddef.h>

#define BATCH 65536
#define OUTF  1024
#define INF   128

typedef float f32x4 __attribute__((ext_vector_type(4)));
typedef __bf16 bf16x8 __attribute__((ext_vector_type(8)));

#define TSTRIDE 1028  // LDS row stride (floats): 1024 + 4 -> 2-way conflicts only, 16B-aligned rows

// RNE float->bf16, packed pair
__device__ inline uint32_t pack_bf16_rne(float a, float b) {
    uint32_t ua = __builtin_bit_cast(uint32_t, a);
    uint32_t ub = __builtin_bit_cast(uint32_t, b);
    ua += 0x7fffu + ((ua >> 16) & 1u);
    ub += 0x7fffu + ((ub >> 16) & 1u);
    return (ua >> 16) | (ub & 0xffff0000u);
}

// Load 8 contiguous fp32, accumulate sum of squares, return bf16x8 fragment.
__device__ inline bf16x8 load_frag_x2(const float* __restrict__ p, float& s) {
    f32x4 v0 = *(const f32x4*)(p);
    f32x4 v1 = *(const f32x4*)(p + 4);
    s += v0.x * v0.x + v0.y * v0.y + v0.z * v0.z + v0.w * v0.w
       + v1.x * v1.x + v1.y * v1.y + v1.z * v1.z + v1.w * v1.w;
    union { uint32_t u[4]; bf16x8 b; } f;
    f.u[0] = pack_bf16_rne(v0.x, v0.y);
    f.u[1] = pack_bf16_rne(v0.z, v0.w);
    f.u[2] = pack_bf16_rne(v1.x, v1.y);
    f.u[3] = pack_bf16_rne(v1.z, v1.w);
    return f.b;
}

// W-only prep: one wave per w-row -> bf16 row + sumsq. 1024 rows, tiny.
__global__ __launch_bounds__(256) void wprep_kernel(
        const float* __restrict__ w, float* __restrict__ w2,
        uint32_t* __restrict__ wb) {
    int gtid = blockIdx.x * 256 + threadIdx.x;
    int row  = gtid >> 6;
    int lane = threadIdx.x & 63;
    if (row >= OUTF) return;
    const float* src = w + (size_t)row * INF;
    float2 v = *(const float2*)(src + lane * 2);
    wb[(size_t)row * 64 + lane] = pack_bf16_rne(v.x, v.y);
    float s = v.x * v.x + v.y * v.y;
    #pragma unroll
    for (int off = 32; off; off >>= 1) s += __shfl_down(s, off);
    if (lane == 0) w2[row] = s;
}

// DRAM-locality-oriented fused kernel: block = 16 x-rows x ALL 1024 cols.
// Output region per block = 64KB FULLY CONTIGUOUS; each wave stores 4
// complete 4KB rows in consecutive 1KB instructions. 4 waves, each owns a
// 256-col slice. Full-width LDS tile (16 x 1028). Both barriers precede all
// stores; stores drain only at endpgm, overlapped with the co-resident block
// (68.3KB LDS -> 2 blocks/CU).
__global__ __launch_bounds__(256, 2) void fused_kernel(
        const float* __restrict__ x, const __bf16* __restrict__ wb,
        const float* __restrict__ w2, float* __restrict__ out) {
    int tid  = threadIdx.x;
    int wid  = tid >> 6;        // wave -> col slice [wid*256, wid*256+256)
    int lane = tid & 63;
    int l16  = lane & 15;       // fragment row/col
    int lq   = lane >> 4;       // k-quarter (loads) / row-quad (epilogue)

    int rbase = blockIdx.x * 16;   // block's 16 x-rows
    int c0    = wid * 256;

    __shared__ float sw2[OUTF];
    __shared__ float tile[16 * TSTRIDE];
    #pragma unroll
    for (int j = 0; j < 4; ++j)
        sw2[tid + 256 * j] = w2[tid + 256 * j];

    // A fragments: 16 rows (frag row = l16), k = ks*32 + lq*8. 16 VGPR.
    bf16x8 a[4];
    float x2p = 0.f;
    #pragma unroll
    for (int ks = 0; ks < 4; ++ks)
        a[ks] = load_frag_x2(
            &x[(size_t)(rbase + l16) * INF + ks * 32 + lq * 8], x2p);

    // Row sumsq: butterfly over the 4 k-quarter groups -> all lanes have
    // x2 of row l16; redistribute to epilogue rows lq*4+r.
    x2p += __shfl_xor(x2p, 16);
    x2p += __shfl_xor(x2p, 32);
    float x2row[4];
    #pragma unroll
    for (int r = 0; r < 4; ++r)
        x2row[r] = __shfl(x2p, lq * 20 + r);

    // GEMM: 16 rows x 256 cols per wave, K=128.
    f32x4 acc[16];
    #pragma unroll
    for (int in = 0; in < 16; ++in)
        acc[in] = f32x4{0.f, 0.f, 0.f, 0.f};

    #pragma unroll
    for (int ks = 0; ks < 4; ++ks) {
        bf16x8 b[16];
        #pragma unroll
        for (int in = 0; in < 16; ++in)
            b[in] = *(const bf16x8*)(
                wb + (size_t)(c0 + in * 16 + l16) * INF + ks * 32 + lq * 8);
        #pragma unroll
        for (int in = 0; in < 16; ++in)
            acc[in] = __builtin_amdgcn_mfma_f32_16x16x32_bf16(
                a[ks], b[in], acc[in], 0, 0, 0);
    }

    __syncthreads();   // sw2 ready (no stores outstanding yet)

    // Epilogue math into full-width LDS tile.
    // C/D layout (verified): col = l16, row = lq*4 + r.
    #pragma unroll
    for (int in = 0; in < 16; ++in) {
        #pragma unroll
        for (int r = 0; r < 4; ++r) {
            int row = lq * 4 + r;
            int col = c0 + in * 16 + l16;
            float d2 = x2row[r] + sw2[col] - 2.0f * acc[in][r];
            tile[row * TSTRIDE + col] =
                -0.5f * __builtin_amdgcn_sqrtf(fmaxf(d2, 0.0f));
        }
    }
    __syncthreads();   // epilogue writes visible (still no stores outstanding)

    // Store: wave w owns rows w*4..w*4+3; each row = 4KB written in 4
    // consecutive 1KB wave-instructions -> dense 64KB contiguous per block.
    #pragma unroll
    for (int r = 0; r < 4; ++r) {
        int row = wid * 4 + r;
        size_t gbase = (size_t)(rbase + row) * OUTF;
        #pragma unroll
        for (int q = 0; q < 4; ++q) {
            f32x4 v = *(const f32x4*)&tile[row * TSTRIDE + q * 256 + lane * 4];
            __builtin_nontemporal_store(
                v, (f32x4*)&out[gbase + q * 256 + lane * 4]);
        }
    }
}

extern "C" void kernel_launch(void* const* d_in, const int* in_sizes, int n_in,
                              void* d_out, int out_size, void* d_ws, size_t ws_size,
                              hipStream_t stream) {
    const float* x = (const float*)d_in[0];
    const float* w = (const float*)d_in[1];
    float* out = (float*)d_out;

    // ws layout: w2 [1024 f32] at 0; wb (bf16 W, 256KB) at byte 4096.
    char* ws = (char*)d_ws;
    float* w2 = (float*)ws;
    uint32_t* wb_u32 = (uint32_t*)(ws + 4096);
    const __bf16* wb = (const __bf16*)wb_u32;

    wprep_kernel<<<dim3(OUTF / 4), dim3(256), 0, stream>>>(w, w2, wb_u32);
    fused_kernel<<<dim3(BATCH / 16), dim3(256), 0, stream>>>(x, wb, w2, out);
}

// Round 12
// 93.371 us; speedup vs baseline: 1.6368x; 1.6368x over previous
//
#include <hip/hip_runtime.h>
#include <stdint.h>
#include <stddef.h>

#define BATCH 65536
#define OUTF  1024
#define INF   128

typedef float f32x4 __attribute__((ext_vector_type(4)));
typedef __bf16 bf16x8 __attribute__((ext_vector_type(8)));

#define CPAD 68   // wave-scratch row stride (floats): 64 + 4

// RNE float->bf16, packed pair
__device__ inline uint32_t pack_bf16_rne(float a, float b) {
    uint32_t ua = __builtin_bit_cast(uint32_t, a);
    uint32_t ub = __builtin_bit_cast(uint32_t, b);
    ua += 0x7fffu + ((ua >> 16) & 1u);
    ub += 0x7fffu + ((ub >> 16) & 1u);
    return (ua >> 16) | (ub & 0xffff0000u);
}

// Load 8 contiguous fp32, accumulate sum of squares, return bf16x8 fragment.
__device__ inline bf16x8 load_frag_x2(const float* __restrict__ p, float& s) {
    f32x4 v0 = *(const f32x4*)(p);
    f32x4 v1 = *(const f32x4*)(p + 4);
    s += v0.x * v0.x + v0.y * v0.y + v0.z * v0.z + v0.w * v0.w
       + v1.x * v1.x + v1.y * v1.y + v1.z * v1.z + v1.w * v1.w;
    union { uint32_t u[4]; bf16x8 b; } f;
    f.u[0] = pack_bf16_rne(v0.x, v0.y);
    f.u[1] = pack_bf16_rne(v0.z, v0.w);
    f.u[2] = pack_bf16_rne(v1.x, v1.y);
    f.u[3] = pack_bf16_rne(v1.z, v1.w);
    return f.b;
}

// W-only prep: one wave per w-row -> bf16 row + sumsq. 1024 rows, tiny.
__global__ __launch_bounds__(256) void wprep_kernel(
        const float* __restrict__ w, float* __restrict__ w2,
        uint32_t* __restrict__ wb) {
    int gtid = blockIdx.x * 256 + threadIdx.x;
    int row  = gtid >> 6;
    int lane = threadIdx.x & 63;
    if (row >= OUTF) return;
    const float* src = w + (size_t)row * INF;
    float2 v = *(const float2*)(src + lane * 2);
    wb[(size_t)row * 64 + lane] = pack_bf16_rne(v.x, v.y);
    float s = v.x * v.x + v.y * v.y;
    #pragma unroll
    for (int off = 32; off; off >>= 1) s += __shfl_down(s, off);
    if (lane == 0) w2[row] = s;
}

// Load one ks-slice of B: 4 column fragments (16B/lane each).
__device__ inline void loadB(const __bf16* __restrict__ wb, int col0,
                             int kbase, int l16, bf16x8* dst) {
    #pragma unroll
    for (int in = 0; in < 4; ++in)
        dst[in] = *(const bf16x8*)(
            wb + (size_t)(col0 + in * 16 + l16) * INF + kbase);
}

// R10 structure + ks-level B software pipeline. The ONLY structural change vs
// R10: every B-load is issued BEFORE the preceding chunk's stores, so the
// vmcnt wait at load-use has >=16-store slack and stores are never awaited
// in the loop (vmcnt retires in order; loads issued after stores would
// otherwise force a full store drain every chunk).
__global__ __launch_bounds__(256, 2) void fused_kernel(
        const float* __restrict__ x, const __bf16* __restrict__ wb,
        const float* __restrict__ w2, float* __restrict__ out) {
    int tid  = threadIdx.x;
    int wid  = tid >> 6;
    int lane = tid & 63;
    int l16  = lane & 15;   // fragment row/col
    int lq   = lane >> 4;   // k-quarter (loads) / row-quad (epilogue)

    int row_base = blockIdx.x * 128 + wid * 32;   // this wave's 32 rows

    __shared__ float sw2[OUTF];
    __shared__ float scratch[2][4][32 * CPAD];    // [dbuf][wave][row][col]
    #pragma unroll
    for (int j = 0; j < 4; ++j)
        sw2[tid + 256 * j] = w2[tid + 256 * j];

    // A fragments (2 im x 4 ks, 32 VGPR) + per-row sumsq partials, loaded once.
    bf16x8 a[4][2];
    float x2p[2] = {0.f, 0.f};
    #pragma unroll
    for (int ks = 0; ks < 4; ++ks)
        #pragma unroll
        for (int im = 0; im < 2; ++im)
            a[ks][im] = load_frag_x2(
                &x[(size_t)(row_base + im * 16 + l16) * INF + ks * 32 + lq * 8],
                x2p[im]);

    // Row sumsq: butterfly over k-quarter groups.
    #pragma unroll
    for (int im = 0; im < 2; ++im) {
        float s = x2p[im];
        s += __shfl_xor(s, 16);
        s += __shfl_xor(s, 32);
        x2p[im] = s;
    }
    // Epilogue layout redistribute: lane (lq,l16) needs rows lq*4+r.
    float x2row[2][4];
    #pragma unroll
    for (int im = 0; im < 2; ++im)
        #pragma unroll
        for (int r = 0; r < 4; ++r)
            x2row[im][r] = __shfl(x2p[im], lq * 20 + r);

    __syncthreads();   // sw2 ready — the ONLY barrier in this kernel

    // B ping-pong slots, slot = ks&1 (parity consistent across chunks since
    // 4 ks/chunk). Prologue: chunk 0, ks 0.
    bf16x8 Bs[2][4];
    loadB(wb, 0, lq * 8, l16, Bs[0]);

    for (int nc = 0; nc < 16; ++nc) {
        int n0  = nc * 64;
        int n0n = ((nc + 1) & 15) * 64;
        float* buf = scratch[nc & 1][wid];

        f32x4 acc[2][4];
        #pragma unroll
        for (int im = 0; im < 2; ++im)
            #pragma unroll
            for (int in = 0; in < 4; ++in)
                acc[im][in] = f32x4{0.f, 0.f, 0.f, 0.f};

        #pragma unroll
        for (int ks = 0; ks < 4; ++ks) {
            // Prefetch the NEXT ks-slice (next chunk's ks0 at ks==3) —
            // issued before this chunk's stores ever exist.
            if (ks < 3)
                loadB(wb, n0,  (ks + 1) * 32 + lq * 8, l16, Bs[(ks + 1) & 1]);
            else
                loadB(wb, n0n, lq * 8,                 l16, Bs[0]);
            #pragma unroll
            for (int im = 0; im < 2; ++im)
                #pragma unroll
                for (int in = 0; in < 4; ++in)
                    acc[im][in] = __builtin_amdgcn_mfma_f32_16x16x32_bf16(
                        a[ks][im], Bs[ks & 1][in], acc[im][in], 0, 0, 0);
        }

        // Epilogue math into this wave's private scratch.
        // C/D layout: col = l16, row = lq*4 + r (within each 16x16 fragment).
        #pragma unroll
        for (int im = 0; im < 2; ++im) {
            #pragma unroll
            for (int in = 0; in < 4; ++in) {
                #pragma unroll
                for (int r = 0; r < 4; ++r) {
                    int rloc = im * 16 + lq * 4 + r;              // 0..31
                    int col  = in * 16 + l16;
                    float d2 = x2row[im][r] + sw2[n0 + col] - 2.0f * acc[im][in][r];
                    buf[rloc * CPAD + col] =
                        -0.5f * __builtin_amdgcn_sqrtf(fmaxf(d2, 0.0f));
                }
            }
        }
        // Intra-wave ds_write -> ds_read ordering via lgkmcnt; no barrier.

        // Store this wave's 32 rows x 64 cols: NT f32x4, 256B/row segments.
        // Never awaited in-loop; drains async under subsequent chunks.
        #pragma unroll
        for (int k = 0; k < 8; ++k) {
            int row = k * 4 + lq;
            f32x4 v = *(const f32x4*)&buf[row * CPAD + l16 * 4];
            __builtin_nontemporal_store(
                v, (f32x4*)&out[(size_t)(row_base + row) * OUTF + n0 + l16 * 4]);
        }
    }
}

extern "C" void kernel_launch(void* const* d_in, const int* in_sizes, int n_in,
                              void* d_out, int out_size, void* d_ws, size_t ws_size,
                              hipStream_t stream) {
    const float* x = (const float*)d_in[0];
    const float* w = (const float*)d_in[1];
    float* out = (float*)d_out;

    // ws layout: w2 [1024 f32] at 0; wb (bf16 W, 256KB) at byte 4096.
    char* ws = (char*)d_ws;
    float* w2 = (float*)ws;
    uint32_t* wb_u32 = (uint32_t*)(ws + 4096);
    const __bf16* wb = (const __bf16*)wb_u32;

    wprep_kernel<<<dim3(OUTF / 4), dim3(256), 0, stream>>>(w, w2, wb_u32);
    fused_kernel<<<dim3(BATCH / 128), dim3(256), 0, stream>>>(x, wb, w2, out);
}